// Round 1
// baseline (242.693 us; speedup 1.0000x reference)
//
#include <hip/hip_runtime.h>

// PDF sampler (NeRF sample_pdf): one 64-lane wave per ray.
// Phase 1: w = weights + HIST_PAD; wave scan -> cdf[65] in LDS; existing bins[65] in LDS.
// Phase 2: 129 inverse-CDF samples via per-lane binary search (searchsorted right).
// Phase 3: sort(concat(existing, new))[:193] == merge of two sorted arrays, done by
//          parallel merge-ranking (binary search cross-counts), scatter into LDS.
// Phase 4: coalesced write of 193 f32 per ray.

constexpr int kNCoarse = 64;   // coarse bins per ray
constexpr int kNumU    = 129;  // NUM_SAMPLES + 1
constexpr int kNExist  = 65;   // N_COARSE + 1
constexpr int kNMerged = 194;  // 65 + 129
constexpr int kNOut    = 193;  // merged minus last
constexpr int kWavesPerBlock = 4;

__global__ __launch_bounds__(256) void pdf_sampler_kernel(
    const float* __restrict__ weights,
    const float* __restrict__ bins,
    const float* __restrict__ max_bin,
    float* __restrict__ out,
    int n_rays)
{
    const int lane = threadIdx.x & 63;
    const int wid  = threadIdx.x >> 6;
    const int ray  = blockIdx.x * kWavesPerBlock + wid;
    const bool valid = ray < n_rays;

    __shared__ float s_cdf[kWavesPerBlock][kNExist];
    __shared__ float s_exist[kWavesPerBlock][kNExist];
    __shared__ float s_new[kWavesPerBlock][kNumU];
    __shared__ float s_merged[kWavesPerBlock][kNMerged];

    // ---- Phase 1: CDF build ----
    if (valid) {
        float w = weights[(size_t)ray * kNCoarse + lane] + 0.01f;  // HIST_PAD
        // inclusive scan over the 64-lane wave
        float c = w;
        #pragma unroll
        for (int off = 1; off < 64; off <<= 1) {
            float y = __shfl_up(c, off, 64);
            if (lane >= off) c += y;
        }
        float w_sum   = __shfl(c, 63, 64);
        float padding = fmaxf(1e-5f - w_sum, 0.0f);   // EPS; == 0 for these inputs
        float total   = w_sum + padding;
        float numer   = c + (float)(lane + 1) * (padding * (1.0f / 64.0f));
        float cdf     = fminf(numer / total, 1.0f);
        s_cdf[wid][lane + 1] = cdf;
        s_exist[wid][lane]   = bins[(size_t)ray * kNCoarse + lane];
        if (lane == 0) {
            s_cdf[wid][0] = 0.0f;
            s_exist[wid][kNCoarse] = max_bin[ray];
        }
    }
    __syncthreads();

    // ---- Phase 2: inverse-CDF sampling ----
    if (valid) {
        const float* cdfr = s_cdf[wid];
        const float* exr  = s_exist[wid];
        for (int j = lane; j < kNumU; j += 64) {
            float u = ((float)j + 0.5f) * (1.0f / 129.0f);
            // searchsorted(cdf, u, side='right'): count of cdf entries <= u
            int lo = 0, hi = kNExist;
            while (lo < hi) {
                int mid = (lo + hi) >> 1;
                if (cdfr[mid] <= u) lo = mid + 1; else hi = mid;
            }
            int below = lo - 1;
            if (below < 0) below = 0;
            if (below > kNExist - 1) below = kNExist - 1;
            int above = lo;
            if (above > kNExist - 1) above = kNExist - 1;
            float c0 = cdfr[below], c1 = cdfr[above];
            float b0 = exr[below],  b1 = exr[above];
            float denom = c1 - c0;
            float t = 0.0f;
            if (denom > 0.0f) {
                t = (u - c0) / denom;
                t = fminf(fmaxf(t, 0.0f), 1.0f);
            }
            s_new[wid][j] = b0 + t * (b1 - b0);
        }
    }
    __syncthreads();

    // ---- Phase 3: merge-rank scatter (replaces sort of concat) ----
    if (valid) {
        const float* newr = s_new[wid];
        const float* exr  = s_exist[wid];
        float* mr = s_merged[wid];
        // existing[i] -> rank = i + |{ new < v }|   (existing wins ties)
        for (int i = lane; i < kNExist; i += 64) {
            float v = exr[i];
            int lo = 0, hi = kNumU;
            while (lo < hi) {
                int mid = (lo + hi) >> 1;
                if (newr[mid] < v) lo = mid + 1; else hi = mid;
            }
            mr[i + lo] = v;
        }
        // new[j] -> rank = j + |{ exist <= v }|
        for (int j = lane; j < kNumU; j += 64) {
            float v = newr[j];
            int lo = 0, hi = kNExist;
            while (lo < hi) {
                int mid = (lo + hi) >> 1;
                if (exr[mid] <= v) lo = mid + 1; else hi = mid;
            }
            mr[j + lo] = v;
        }
    }
    __syncthreads();

    // ---- Phase 4: coalesced output of first 193 ----
    if (valid) {
        for (int k = lane; k < kNOut; k += 64) {
            out[(size_t)ray * kNOut + k] = s_merged[wid][k];
        }
    }
}

extern "C" void kernel_launch(void* const* d_in, const int* in_sizes, int n_in,
                              void* d_out, int out_size, void* d_ws, size_t ws_size,
                              hipStream_t stream) {
    const float* weights = (const float*)d_in[0];
    const float* bins    = (const float*)d_in[1];
    const float* max_bin = (const float*)d_in[2];
    float* out = (float*)d_out;
    const int n_rays = in_sizes[2];  // max_bin has one element per ray
    const int blocks = (n_rays + kWavesPerBlock - 1) / kWavesPerBlock;
    pdf_sampler_kernel<<<blocks, 256, 0, stream>>>(weights, bins, max_bin, out, n_rays);
}

// Round 2
// 142.507 us; speedup vs baseline: 1.7030x; 1.7030x over previous
//
#include <hip/hip_runtime.h>

// PDF sampler (NeRF sample_pdf): one 64-lane wave per ray, search-free.
//
// Key structure exploited:
//  - u_j = (j+0.5)/129 is uniformly spaced & sorted, cdf is sorted -> each lane
//    (owning cdf interval [c0,c1) = [cdf[lane], cdf[lane+1])) directly computes
//    the contiguous sample range [js, js_next) that falls in its interval.
//    No searchsorted.
//  - Every sample in interval k lies in [exist[k-1], exist[k]] and samples are
//    monotone in u, so sort(concat(exist, new)) is structurally:
//      exist[0], {intv-1 samples}, exist[1], {intv-2 samples}, ..., exist[64]
//    sample j (interval k) -> merged pos j+k ; exist[i] -> pos i + js_{i+1};
//    exist[64] = max_bin lands at pos 193 = the dropped element. No sort.
//  - Scatter into LDS, then coalesced 193-float row write.

constexpr int kNCoarse = 64;   // coarse bins per ray (== wave size)
constexpr int kNumU    = 129;  // NUM_SAMPLES + 1
constexpr int kNOut    = 193;  // output samples per ray
constexpr int kWaves   = 4;    // waves (rays) per block

__global__ __launch_bounds__(256) void pdf_sampler_kernel(
    const float* __restrict__ weights,
    const float* __restrict__ bins,
    const float* __restrict__ max_bin,
    float* __restrict__ out,
    int n_rays)
{
    const int lane = threadIdx.x & 63;
    const int wid  = threadIdx.x >> 6;
    const int ray  = blockIdx.x * kWaves + wid;
    const bool valid = ray < n_rays;

    __shared__ float s_m[kWaves][kNOut];

    // ---- load (coalesced: 256B/wave each) ----
    float w = 0.0f, b0 = 0.0f, mb = 0.0f;
    if (valid) {
        w  = weights[(size_t)ray * kNCoarse + lane] + 0.01f;   // HIST_PAD
        b0 = bins[(size_t)ray * kNCoarse + lane];
        if (lane == 63) mb = max_bin[ray];
    }

    // ---- wave sum of w (butterfly) ----
    float ws = w;
    #pragma unroll
    for (int off = 32; off >= 1; off >>= 1) ws += __shfl_xor(ws, off, 64);

    const float padding = fmaxf(1e-5f - ws, 0.0f);   // EPS pad (0 for these inputs)
    const float total   = ws + padding;
    const float pdf     = (w + padding * (1.0f / 64.0f)) / total;

    // ---- inclusive wave scan of pdf -> cdf ----
    float c = pdf;
    #pragma unroll
    for (int off = 1; off < 64; off <<= 1) {
        float y = __shfl_up(c, off, 64);
        if (lane >= off) c += y;
    }
    const float c1 = fminf(c, 1.0f);                 // cdf[lane+1]
    float c0 = __shfl_up(c1, 1, 64);                 // cdf[lane]
    if (lane == 0) c0 = 0.0f;

    // neighbor bin (b1 = exist[lane+1]; lane 63 uses max_bin)
    float b1 = __shfl_down(b0, 1, 64);
    if (lane == 63) b1 = mb;

    // ---- first sample index in this lane's interval: js = min{j : u_j >= c0} ----
    const float kInv = 1.0f / 129.0f;
    int js = (int)floorf(c0 * 129.0f + 0.5f);
    js = min(max(js, 0), kNumU);
    while (js > 0      && ((float)(js - 1) + 0.5f) * kInv >= c0) --js;
    while (js < kNumU  && ((float)js       + 0.5f) * kInv <  c0) ++js;

    int js_next = __shfl_down(js, 1, 64);
    if (lane == 63) js_next = kNumU;

    if (!valid) { js = 0; js_next = 0; }

    // ---- emit this lane's samples + its existing bin into merged positions ----
    const float denom = c1 - c0;
    const float dbin  = b1 - b0;
    for (int j = js; j < js_next; ++j) {
        float u = ((float)j + 0.5f) * kInv;
        float t = 0.0f;
        if (denom > 0.0f) t = fminf(fmaxf((u - c0) / denom, 0.0f), 1.0f);
        s_m[wid][j + lane + 1] = b0 + t * dbin;      // pos = j + k, k = lane+1
    }
    if (valid) s_m[wid][lane + js] = b0;             // exist[lane] at i + js_{i+1} (<=192)

    __syncthreads();

    // ---- coalesced row write ----
    if (valid) {
        const size_t base = (size_t)ray * kNOut;
        #pragma unroll
        for (int k = lane; k < kNOut; k += 64) out[base + k] = s_m[wid][k];
    }
}

extern "C" void kernel_launch(void* const* d_in, const int* in_sizes, int n_in,
                              void* d_out, int out_size, void* d_ws, size_t ws_size,
                              hipStream_t stream) {
    const float* weights = (const float*)d_in[0];
    const float* bins    = (const float*)d_in[1];
    const float* max_bin = (const float*)d_in[2];
    float* out = (float*)d_out;
    const int n_rays = in_sizes[2];  // one max_bin entry per ray
    const int blocks = (n_rays + kWaves - 1) / kWaves;
    pdf_sampler_kernel<<<blocks, 256, 0, stream>>>(weights, bins, max_bin, out, n_rays);
}

// Round 3
// 108.608 us; speedup vs baseline: 2.2346x; 1.3121x over previous
//
#include <hip/hip_runtime.h>

// PDF sampler (NeRF sample_pdf): one 64-lane wave per ray, search-free, shuffle-free.
//
//  - Wave-wide inclusive scan via DPP (row_shr 1/2/4/8 + row_bcast 15/31): pure VALU,
//    no LDS-pipe ds_bpermute traffic (every __shfl on CDNA is an LDS op -> that pipe
//    was the R1 bottleneck).
//  - Single scan: cumsum(pdf)[k] = (cumsum(w)[k] + (k+1)*pad/64) / total.
//  - u_j uniform & sorted  ->  each lane's cdf interval [c0,c1) owns a contiguous
//    sample range [js, js_next): O(1) estimate + <=1-step fixup, no searchsorted.
//  - sort(concat(exist,new)) is structurally a merge with known ranks:
//    sample j (interval k=lane+1) -> pos j+k ; exist[lane] -> pos lane+js(lane);
//    exist[64]=max_bin lands at pos 193 = the dropped element. No sort.
//  - Per-wave private LDS row; no __syncthreads (explicit lgkmcnt drain only).

constexpr int kNCoarse = 64;   // coarse bins per ray (== wave size)
constexpr int kNumU    = 129;  // NUM_SAMPLES + 1
constexpr int kNOut    = 193;  // output samples per ray
constexpr int kWaves   = 8;    // waves (rays) per block
constexpr int kBlock   = kWaves * 64;

// DPP update: dest = (lane receives src per ctrl) if valid/unmasked else old.
#define DPP_UPD_F(oldv, srcv, ctrl, rmask, bctrl)                             \
  __int_as_float(__builtin_amdgcn_update_dpp(                                 \
      __float_as_int(oldv), __float_as_int(srcv), (ctrl), (rmask), 0xF, (bctrl)))

__global__ __launch_bounds__(kBlock) void pdf_sampler_kernel(
    const float* __restrict__ weights,
    const float* __restrict__ bins,
    const float* __restrict__ max_bin,
    float* __restrict__ out,
    int n_rays)
{
    const int lane = threadIdx.x & 63;
    const int wid  = threadIdx.x >> 6;
    const int ray  = blockIdx.x * kWaves + wid;

    __shared__ float s_m[kWaves][kNOut];

    if (ray >= n_rays) return;   // wave-uniform; no barriers in kernel -> safe

    // ---- loads (coalesced 256 B/wave; max_bin is wave-uniform -> scalar load) ----
    const float w  = weights[(size_t)ray * kNCoarse + lane] + 0.01f;  // HIST_PAD
    const float b0 = bins[(size_t)ray * kNCoarse + lane];
    const float mb = max_bin[ray];

    // ---- wave64 inclusive scan of w via DPP (all VALU, no LDS) ----
    float c = w;
    c += DPP_UPD_F(0.0f, c, 0x111, 0xF, true);   // row_shr:1
    c += DPP_UPD_F(0.0f, c, 0x112, 0xF, true);   // row_shr:2
    c += DPP_UPD_F(0.0f, c, 0x114, 0xF, true);   // row_shr:4
    c += DPP_UPD_F(0.0f, c, 0x118, 0xF, true);   // row_shr:8
    c += DPP_UPD_F(0.0f, c, 0x142, 0xA, false);  // row_bcast:15 -> rows 1,3
    c += DPP_UPD_F(0.0f, c, 0x143, 0xC, false);  // row_bcast:31 -> rows 2,3

    const float ws = __int_as_float(__builtin_amdgcn_readlane(__float_as_int(c), 63));
    const float padding   = fmaxf(1e-5f - ws, 0.0f);      // EPS pad (0 for these inputs)
    const float inv_total = 1.0f / (ws + padding);
    const float pad64     = padding * (1.0f / 64.0f);

    const float c1 = fminf((c + (float)(lane + 1) * pad64) * inv_total, 1.0f); // cdf[lane+1]
    const float c0 = DPP_UPD_F(0.0f, c1, 0x138, 0xF, true);  // wf_sr:1 -> cdf[lane], lane0=0
    const float b1 = DPP_UPD_F(mb,   b0, 0x130, 0xF, false); // wf_sl:1 -> exist[lane+1], lane63=mb

    // ---- first sample index in this lane's interval: js = min{j : u_j >= c0} ----
    const float kInv = 1.0f / 129.0f, kHalf = 0.5f / 129.0f;
    int js = (int)floorf(c0 * 129.0f + 0.5f);
    js = min(max(js, 0), kNumU);
    while (js > 0     && fmaf((float)(js - 1), kInv, kHalf) >= c0) --js;
    while (js < kNumU && fmaf((float)js,       kInv, kHalf) <  c0) ++js;

    const int js_next = __builtin_amdgcn_update_dpp(kNumU, js, 0x130, 0xF, 0xF, false); // lane63=129

    // ---- emit samples + existing bin at exact merged ranks ----
    const float denom  = c1 - c0;
    const float rdenom = (denom > 0.0f) ? (1.0f / denom) : 0.0f;
    const float nc0rd  = -c0 * rdenom;
    const float dbin   = b1 - b0;
    float* mrow = s_m[wid];

    mrow[lane + js] = b0;                         // exist[lane] at rank lane + js
    for (int j = js; j < js_next; ++j) {
        float u = fmaf((float)j, kInv, kHalf);
        float t = fminf(fmaxf(fmaf(u, rdenom, nc0rd), 0.0f), 1.0f);
        mrow[j + lane + 1] = fmaf(t, dbin, b0);   // sample j at rank j + (lane+1)
    }

    // drain our wave's LDS writes (no cross-wave sharing -> no __syncthreads)
    asm volatile("s_waitcnt lgkmcnt(0)" ::: "memory");

    // ---- coalesced row write ----
    const size_t base = (size_t)ray * kNOut;
    #pragma unroll
    for (int k = 0; k < 4; ++k) {
        int idx = lane + 64 * k;
        if (idx < kNOut) out[base + idx] = mrow[idx];
    }
}

extern "C" void kernel_launch(void* const* d_in, const int* in_sizes, int n_in,
                              void* d_out, int out_size, void* d_ws, size_t ws_size,
                              hipStream_t stream) {
    const float* weights = (const float*)d_in[0];
    const float* bins    = (const float*)d_in[1];
    const float* max_bin = (const float*)d_in[2];
    float* out = (float*)d_out;
    const int n_rays = in_sizes[2];  // one max_bin entry per ray
    const int blocks = (n_rays + kWaves - 1) / kWaves;
    pdf_sampler_kernel<<<blocks, kBlock, 0, stream>>>(weights, bins, max_bin, out, n_rays);
}

// Round 4
// 107.165 us; speedup vs baseline: 2.2647x; 1.0135x over previous
//
#include <hip/hip_runtime.h>

// PDF sampler (NeRF sample_pdf): one 64-lane wave per ray.
// Search-free, sort-free, shuffle-free, LDS-free.
//
//  - DPP wave64 inclusive scan (row_shr 1/2/4/8 + row_bcast 15/31): pure VALU.
//  - u_j = (j+0.5)/129 uniform & sorted -> each lane's cdf interval [c0,c1)
//    owns the contiguous sample range [js, js_next); js by O(1) ceil estimate
//    + one branchless fixup (float error << sample spacing => off-by-1 max).
//  - sort(concat(exist,new)) has closed-form ranks: sample j (interval k=lane+1)
//    -> rank j+k ; exist[lane] -> rank lane+js ; exist[64]=max_bin -> rank 193,
//    the dropped element. Lane's writes are a contiguous run [lane+js, lane+js_next],
//    runs tile [0,193) exactly -> direct global stores, dense within 772 B/wave,
//    L2 write-combines. No LDS round-trip at all.
//  - Within an interval, sample values form an arithmetic sequence -> loop body
//    is store + add.

constexpr int kNCoarse = 64;   // coarse bins per ray (== wave size)
constexpr int kNumU    = 129;  // NUM_SAMPLES + 1
constexpr int kNOut    = 193;  // output samples per ray
constexpr int kWaves   = 8;    // rays per block
constexpr int kBlock   = kWaves * 64;

// DPP update: lanes receive src per ctrl; invalid lanes keep oldv (bctrl=false) or 0 (true).
#define DPP_UPD_F(oldv, srcv, ctrl, rmask, bctrl)                             \
  __int_as_float(__builtin_amdgcn_update_dpp(                                 \
      __float_as_int(oldv), __float_as_int(srcv), (ctrl), (rmask), 0xF, (bctrl)))

__global__ __launch_bounds__(kBlock) void pdf_sampler_kernel(
    const float* __restrict__ weights,
    const float* __restrict__ bins,
    const float* __restrict__ max_bin,
    float* __restrict__ out,
    int n_rays)
{
    const int lane = threadIdx.x & 63;
    const int wid  = threadIdx.x >> 6;
    const int ray  = blockIdx.x * kWaves + wid;
    if (ray >= n_rays) return;          // wave-uniform, no barriers in kernel

    // ---- loads (coalesced 256 B/wave; max_bin wave-uniform -> scalar load) ----
    const float w  = weights[(size_t)ray * kNCoarse + lane] + 0.01f;  // HIST_PAD
    const float b0 = bins[(size_t)ray * kNCoarse + lane];
    const float mb = max_bin[ray];

    // ---- wave64 inclusive scan of w via DPP (6 VALU ops) ----
    float c = w;
    c += DPP_UPD_F(0.0f, c, 0x111, 0xF, true);   // row_shr:1
    c += DPP_UPD_F(0.0f, c, 0x112, 0xF, true);   // row_shr:2
    c += DPP_UPD_F(0.0f, c, 0x114, 0xF, true);   // row_shr:4
    c += DPP_UPD_F(0.0f, c, 0x118, 0xF, true);   // row_shr:8
    c += DPP_UPD_F(0.0f, c, 0x142, 0xA, false);  // row_bcast:15 -> rows 1,3
    c += DPP_UPD_F(0.0f, c, 0x143, 0xC, false);  // row_bcast:31 -> rows 2,3

    const float ws        = __int_as_float(__builtin_amdgcn_readlane(__float_as_int(c), 63));
    const float padding   = fmaxf(1e-5f - ws, 0.0f);       // EPS pad (0 for these inputs)
    const float inv_total = __builtin_amdgcn_rcpf(ws + padding);   // ~1ulp, thr=0.098
    const float pad64     = padding * (1.0f / 64.0f);

    const float c1 = fminf((c + (float)(lane + 1) * pad64) * inv_total, 1.0f); // cdf[lane+1]
    const float c0 = DPP_UPD_F(0.0f, c1, 0x138, 0xF, true);   // wf_sr:1 -> cdf[lane], lane0=0
    const float b1 = DPP_UPD_F(mb,   b0, 0x130, 0xF, false);  // wf_sl:1 -> exist[lane+1], lane63=mb

    // ---- js = min{j : u_j >= c0}: ceil estimate + one branchless fixup ----
    const float kInv = 1.0f / 129.0f, kHalf = 0.5f / 129.0f;
    int js = (int)ceilf(fmaf(c0, 129.0f, -0.5f));
    js = min(max(js, 0), kNumU);
    {
        const float um1 = fmaf((float)(js - 1), kInv, kHalf);
        const float u0e = fmaf((float)js,       kInv, kHalf);
        if (js > 0 && um1 >= c0)           js -= 1;   // mutually exclusive with:
        else if (js < kNumU && u0e < c0)   js += 1;
    }
    const int js_next = __builtin_amdgcn_update_dpp(kNumU, js, 0x130, 0xF, 0xF, false);

    // ---- interpolation as arithmetic sequence over this lane's samples ----
    const float denom  = c1 - c0;
    const float rdenom = (denom > 0.0f) ? __builtin_amdgcn_rcpf(denom) : 0.0f;
    const float dbin   = b1 - b0;
    const float u0     = fmaf((float)js, kInv, kHalf);
    const float t0     = fminf(fmaxf((u0 - c0) * rdenom, 0.0f), 1.0f);
    float       val    = fmaf(t0, dbin, b0);
    const float step   = kInv * rdenom * dbin;

    // ---- direct global emit at exact merged ranks ----
    float* orow = out + (size_t)ray * kNOut;
    orow[lane + js] = b0;                       // exist[lane] at rank lane+js (<=192)
    for (int j = js; j < js_next; ++j) {        // samples at ranks j+lane+1
        orow[j + lane + 1] = val;
        val += step;
    }
}

extern "C" void kernel_launch(void* const* d_in, const int* in_sizes, int n_in,
                              void* d_out, int out_size, void* d_ws, size_t ws_size,
                              hipStream_t stream) {
    const float* weights = (const float*)d_in[0];
    const float* bins    = (const float*)d_in[1];
    const float* max_bin = (const float*)d_in[2];
    float* out = (float*)d_out;
    const int n_rays = in_sizes[2];  // one max_bin entry per ray
    const int blocks = (n_rays + kWaves - 1) / kWaves;
    pdf_sampler_kernel<<<blocks, kBlock, 0, stream>>>(weights, bins, max_bin, out, n_rays);
}

// Round 5
// 77.457 us; speedup vs baseline: 3.1332x; 1.3835x over previous
//
#include <hip/hip_runtime.h>

// PDF sampler (NeRF sample_pdf): one 64-lane wave per ray.
// Search-free, sort-free, shuffle-free; LDS used ONLY as a write-coalescing
// staging buffer (scatter per-ray, then block-wide aligned float4 writeback).
//
//  - DPP wave64 inclusive scan (row_shr 1/2/4/8 + row_bcast 15/31): pure VALU.
//  - u_j = (j+0.5)/129 uniform & sorted -> each lane's cdf interval [c0,c1)
//    owns the contiguous sample range [js, js_next); O(1) estimate + 1 fixup.
//  - sort(concat(exist,new)) has closed-form ranks: sample j (interval k=lane+1)
//    -> rank j+k ; exist[lane] -> rank lane+js ; exist[64]=max_bin -> rank 193
//    = the dropped element. No sort, no search.
//  - R3 lesson: direct scattered global stores amplify write transactions ~4x
//    (9 store instrs x up to 13 lines each). Stage rows in LDS, then the block
//    writes its 8 rays' 6176 B contiguously as 386 aligned dwordx4 stores.

constexpr int kNCoarse = 64;            // coarse bins per ray (== wave size)
constexpr int kNumU    = 129;           // NUM_SAMPLES + 1
constexpr int kNOut    = 193;           // output samples per ray
constexpr int kWaves   = 8;             // rays per block
constexpr int kBlock   = kWaves * 64;   // 512 threads
constexpr int kBlockF  = kWaves * kNOut;   // 1544 floats staged per block
constexpr int kBlockV4 = kBlockF / 4;      // 386 float4 stores per block

// DPP update: lanes receive src per ctrl; invalid lanes keep oldv (bctrl=false) or 0 (true).
#define DPP_UPD_F(oldv, srcv, ctrl, rmask, bctrl)                             \
  __int_as_float(__builtin_amdgcn_update_dpp(                                 \
      __float_as_int(oldv), __float_as_int(srcv), (ctrl), (rmask), 0xF, (bctrl)))

__global__ __launch_bounds__(kBlock) void pdf_sampler_kernel(
    const float* __restrict__ weights,
    const float* __restrict__ bins,
    const float* __restrict__ max_bin,
    float* __restrict__ out,
    int n_rays)
{
    const int tid  = threadIdx.x;
    const int lane = tid & 63;
    const int wid  = tid >> 6;
    const int ray  = blockIdx.x * kWaves + wid;

    __shared__ __align__(16) float s_m[kBlockF];

    if (ray < n_rays) {
        // ---- loads (coalesced 256 B/wave; max_bin wave-uniform) ----
        const float w  = weights[(size_t)ray * kNCoarse + lane] + 0.01f;  // HIST_PAD
        const float b0 = bins[(size_t)ray * kNCoarse + lane];
        const float mb = max_bin[ray];

        // ---- wave64 inclusive scan of w via DPP (6 VALU ops) ----
        float c = w;
        c += DPP_UPD_F(0.0f, c, 0x111, 0xF, true);   // row_shr:1
        c += DPP_UPD_F(0.0f, c, 0x112, 0xF, true);   // row_shr:2
        c += DPP_UPD_F(0.0f, c, 0x114, 0xF, true);   // row_shr:4
        c += DPP_UPD_F(0.0f, c, 0x118, 0xF, true);   // row_shr:8
        c += DPP_UPD_F(0.0f, c, 0x142, 0xA, false);  // row_bcast:15 -> rows 1,3
        c += DPP_UPD_F(0.0f, c, 0x143, 0xC, false);  // row_bcast:31 -> rows 2,3

        const float ws        = __int_as_float(__builtin_amdgcn_readlane(__float_as_int(c), 63));
        const float padding   = fmaxf(1e-5f - ws, 0.0f);     // EPS pad (0 for these inputs)
        const float inv_total = __builtin_amdgcn_rcpf(ws + padding);  // ~1ulp, thr=0.098
        const float pad64     = padding * (1.0f / 64.0f);

        const float c1 = fminf((c + (float)(lane + 1) * pad64) * inv_total, 1.0f); // cdf[lane+1]
        const float c0 = DPP_UPD_F(0.0f, c1, 0x138, 0xF, true);   // wf_sr:1 -> cdf[lane]
        const float b1 = DPP_UPD_F(mb,   b0, 0x130, 0xF, false);  // wf_sl:1 -> exist[lane+1]

        // ---- js = min{j : u_j >= c0}: estimate + one branchless fixup ----
        const float kInv = 1.0f / 129.0f, kHalf = 0.5f / 129.0f;
        int js = (int)ceilf(fmaf(c0, 129.0f, -0.5f));
        js = min(max(js, 0), kNumU);
        {
            const float um1 = fmaf((float)(js - 1), kInv, kHalf);
            const float u0e = fmaf((float)js,       kInv, kHalf);
            if (js > 0 && um1 >= c0)           js -= 1;
            else if (js < kNumU && u0e < c0)   js += 1;
        }
        const int js_next = __builtin_amdgcn_update_dpp(kNumU, js, 0x130, 0xF, 0xF, false);

        // ---- interpolation as arithmetic sequence over this lane's samples ----
        const float denom  = c1 - c0;
        const float rdenom = (denom > 0.0f) ? __builtin_amdgcn_rcpf(denom) : 0.0f;
        const float dbin   = b1 - b0;
        const float u0     = fmaf((float)js, kInv, kHalf);
        const float t0     = fminf(fmaxf((u0 - c0) * rdenom, 0.0f), 1.0f);
        float       val    = fmaf(t0, dbin, b0);
        const float step   = kInv * rdenom * dbin;

        // ---- scatter into this ray's LDS row at exact merged ranks ----
        float* mrow = s_m + wid * kNOut;
        mrow[lane + js] = b0;                       // exist[lane] at rank lane+js (<=192)
        for (int j = js; j < js_next; ++j) {        // samples at ranks j+lane+1
            mrow[j + lane + 1] = val;
            val += step;
        }
    }

    __syncthreads();   // drains LDS writes (compiler emits lgkmcnt(0) before barrier)

    // ---- block-wide coalesced writeback: 8 rays = 6176 B contiguous, 16B-aligned ----
    {
        const int raysHere = min(n_rays - blockIdx.x * kWaves, kWaves);
        if (raysHere > 0) {
            const int nf = raysHere * kNOut;
            float* obase = out + (size_t)blockIdx.x * kBlockF;
            if (tid < kBlockV4) {
                const int off = tid * 4;
                if (off + 3 < nf) {
                    *reinterpret_cast<float4*>(&obase[off]) =
                        *reinterpret_cast<const float4*>(&s_m[off]);
                } else {
                    for (int k = off; k < nf; ++k) obase[k] = s_m[k];  // <=3 tail elems
                }
            }
        }
    }
}

extern "C" void kernel_launch(void* const* d_in, const int* in_sizes, int n_in,
                              void* d_out, int out_size, void* d_ws, size_t ws_size,
                              hipStream_t stream) {
    const float* weights = (const float*)d_in[0];
    const float* bins    = (const float*)d_in[1];
    const float* max_bin = (const float*)d_in[2];
    float* out = (float*)d_out;
    const int n_rays = in_sizes[2];  // one max_bin entry per ray
    const int blocks = (n_rays + kWaves - 1) / kWaves;
    pdf_sampler_kernel<<<blocks, kBlock, 0, stream>>>(weights, bins, max_bin, out, n_rays);
}

// Round 7
// 55.696 us; speedup vs baseline: 4.3575x; 1.3907x over previous
//
#include <hip/hip_runtime.h>

// PDF sampler (NeRF sample_pdf): one 64-lane wave per ray.
// Search-free, sort-free, shuffle-free; LDS used ONLY as a write-coalescing
// staging buffer (scatter per-ray, then block-wide aligned float4 writeback).
// R6 == R5 with the nontemporal-store type fixed: __builtin_nontemporal_store
// requires a NATIVE vector type (ext_vector_type), not HIP's float4 struct.
//
//  - DPP wave64 inclusive scan (row_shr 1/2/4/8 + row_bcast 15/31): pure VALU.
//  - u_j = (j+0.5)/129 uniform & sorted -> each lane's cdf interval [c0,c1)
//    owns the contiguous sample range [js, js_next); O(1) estimate + 1 fixup.
//  - sort(concat(exist,new)) has closed-form ranks: sample j (interval k=lane+1)
//    -> rank j+k ; exist[lane] -> rank lane+js ; exist[64]=max_bin -> rank 193
//    = the dropped element. No sort, no search.
//  - Stage rows in LDS, then the block writes its 8 rays' 6176 B contiguously
//    as 386 aligned nontemporal dwordx4 stores (evict-first: output stream must
//    not evict the L3-resident inputs).

constexpr int kNCoarse = 64;            // coarse bins per ray (== wave size)
constexpr int kNumU    = 129;           // NUM_SAMPLES + 1
constexpr int kNOut    = 193;           // output samples per ray
constexpr int kWaves   = 8;             // rays per block
constexpr int kBlock   = kWaves * 64;   // 512 threads
constexpr int kBlockF  = kWaves * kNOut;   // 1544 floats staged per block
constexpr int kBlockV4 = kBlockF / 4;      // 386 float4 stores per block

typedef float f32x4 __attribute__((ext_vector_type(4)));   // native vector for nt-store

// DPP update: lanes receive src per ctrl; invalid lanes keep oldv (bctrl=false) or 0 (true).
#define DPP_UPD_F(oldv, srcv, ctrl, rmask, bctrl)                             \
  __int_as_float(__builtin_amdgcn_update_dpp(                                 \
      __float_as_int(oldv), __float_as_int(srcv), (ctrl), (rmask), 0xF, (bctrl)))

__global__ __launch_bounds__(kBlock) void pdf_sampler_kernel(
    const float* __restrict__ weights,
    const float* __restrict__ bins,
    const float* __restrict__ max_bin,
    float* __restrict__ out,
    int n_rays)
{
    const int tid  = threadIdx.x;
    const int lane = tid & 63;
    const int wid  = tid >> 6;
    const int ray  = blockIdx.x * kWaves + wid;

    __shared__ __align__(16) float s_m[kBlockF];

    if (ray < n_rays) {
        // ---- loads (coalesced 256 B/wave; max_bin wave-uniform) ----
        const float w  = weights[(size_t)ray * kNCoarse + lane] + 0.01f;  // HIST_PAD
        const float b0 = bins[(size_t)ray * kNCoarse + lane];
        const float mb = max_bin[ray];

        // ---- wave64 inclusive scan of w via DPP (6 VALU ops) ----
        float c = w;
        c += DPP_UPD_F(0.0f, c, 0x111, 0xF, true);   // row_shr:1
        c += DPP_UPD_F(0.0f, c, 0x112, 0xF, true);   // row_shr:2
        c += DPP_UPD_F(0.0f, c, 0x114, 0xF, true);   // row_shr:4
        c += DPP_UPD_F(0.0f, c, 0x118, 0xF, true);   // row_shr:8
        c += DPP_UPD_F(0.0f, c, 0x142, 0xA, false);  // row_bcast:15 -> rows 1,3
        c += DPP_UPD_F(0.0f, c, 0x143, 0xC, false);  // row_bcast:31 -> rows 2,3

        const float ws        = __int_as_float(__builtin_amdgcn_readlane(__float_as_int(c), 63));
        const float padding   = fmaxf(1e-5f - ws, 0.0f);     // EPS pad (0 for these inputs)
        const float inv_total = __builtin_amdgcn_rcpf(ws + padding);  // ~1ulp, thr=0.098
        const float pad64     = padding * (1.0f / 64.0f);

        const float c1 = fminf((c + (float)(lane + 1) * pad64) * inv_total, 1.0f); // cdf[lane+1]
        const float c0 = DPP_UPD_F(0.0f, c1, 0x138, 0xF, true);   // wf_sr:1 -> cdf[lane]
        const float b1 = DPP_UPD_F(mb,   b0, 0x130, 0xF, false);  // wf_sl:1 -> exist[lane+1]

        // ---- js = min{j : u_j >= c0}: estimate + one branchless fixup ----
        const float kInv = 1.0f / 129.0f, kHalf = 0.5f / 129.0f;
        int js = (int)ceilf(fmaf(c0, 129.0f, -0.5f));
        js = min(max(js, 0), kNumU);
        {
            const float um1 = fmaf((float)(js - 1), kInv, kHalf);
            const float u0e = fmaf((float)js,       kInv, kHalf);
            if (js > 0 && um1 >= c0)           js -= 1;
            else if (js < kNumU && u0e < c0)   js += 1;
        }
        const int js_next = __builtin_amdgcn_update_dpp(kNumU, js, 0x130, 0xF, 0xF, false);

        // ---- interpolation as arithmetic sequence over this lane's samples ----
        const float denom  = c1 - c0;
        const float rdenom = (denom > 0.0f) ? __builtin_amdgcn_rcpf(denom) : 0.0f;
        const float dbin   = b1 - b0;
        const float u0     = fmaf((float)js, kInv, kHalf);
        const float t0     = fminf(fmaxf((u0 - c0) * rdenom, 0.0f), 1.0f);
        float       val    = fmaf(t0, dbin, b0);
        const float step   = kInv * rdenom * dbin;

        // ---- scatter into this ray's LDS row at exact merged ranks ----
        float* mrow = s_m + wid * kNOut;
        mrow[lane + js] = b0;                       // exist[lane] at rank lane+js (<=192)
        for (int j = js; j < js_next; ++j) {        // samples at ranks j+lane+1
            mrow[j + lane + 1] = val;
            val += step;
        }
    }

    __syncthreads();   // drains LDS writes (compiler emits lgkmcnt(0) before barrier)

    // ---- block-wide coalesced writeback, non-temporal (don't pollute L2/L3) ----
    {
        const int raysHere = min(n_rays - blockIdx.x * kWaves, kWaves);
        if (raysHere > 0) {
            const int nf = raysHere * kNOut;
            float* obase = out + (size_t)blockIdx.x * kBlockF;
            if (tid < kBlockV4) {
                const int off = tid * 4;
                if (off + 3 < nf) {
                    const f32x4 v = *reinterpret_cast<const f32x4*>(&s_m[off]);
                    __builtin_nontemporal_store(v, reinterpret_cast<f32x4*>(&obase[off]));
                } else {
                    for (int k = off; k < nf; ++k)
                        __builtin_nontemporal_store(s_m[k], &obase[k]);  // <=3 tail elems
                }
            }
        }
    }
}

extern "C" void kernel_launch(void* const* d_in, const int* in_sizes, int n_in,
                              void* d_out, int out_size, void* d_ws, size_t ws_size,
                              hipStream_t stream) {
    const float* weights = (const float*)d_in[0];
    const float* bins    = (const float*)d_in[1];
    const float* max_bin = (const float*)d_in[2];
    float* out = (float*)d_out;
    const int n_rays = in_sizes[2];  // one max_bin entry per ray
    const int blocks = (n_rays + kWaves - 1) / kWaves;
    pdf_sampler_kernel<<<blocks, kBlock, 0, stream>>>(weights, bins, max_bin, out, n_rays);
}